// Round 6
// baseline (241.939 us; speedup 1.0000x reference)
//
#include <hip/hip_runtime.h>

#define BB 4
#define NN 16384
#define SS 4096
#define CIN 256
#define COUT 256

#define SC 8                  // s-chunks per knn block pass
#define SCS (SS / SC)         // 512 candidates staged per knn block
#define SUBS 16               // value-dump granularity: 16 subs of 256
#define SUBL 256
#define KNNB ((NN / 512) * SC * BB)           // 32*8*4 = 1024 knn blocks (NPT=2)
#define GEMMB ((COUT / 64) * (SS / 64) * BB)  // 4*64*4 = 1024 gemm blocks
#define RSLVB (BB * (NN / 64))                // 1024 resolve blocks (64 q x 4 slots)

typedef float v2f __attribute__((ext_vector_type(2)));
typedef float v4f __attribute__((ext_vector_type(4)));

__device__ __forceinline__ unsigned short f2bf(float f) {   // RNE float->bf16
    unsigned u = __float_as_uint(f);
    u += 0x7FFF + ((u >> 16) & 1);
    return (unsigned short)(u >> 16);
}
__device__ __forceinline__ float bf2f(unsigned short h) {
    return __uint_as_float((unsigned)h << 16);
}

// Exact stable top-3 insert, f32 values + explicit index tracking.
// Strict '<' + ascending-index processing == reference stable top_k
// tie-break (proven passing round 3/5).
__device__ __forceinline__ void insert_vi(float e, int gi,
                                          float& k0, float& k1, float& k2,
                                          int& i0, int& i1, int& i2) {
    bool c0 = e < k0, c1 = e < k1, c2 = e < k2;
    float n0 = fminf(e, k0);
    float n1 = __builtin_amdgcn_fmed3f(e, k0, k1);
    float n2 = __builtin_amdgcn_fmed3f(e, k1, k2);
    int t1 = c0 ? i0 : gi;
    int t2 = c1 ? i1 : gi;
    i0 = c0 ? gi : i0;
    i1 = c1 ? t1 : i1;
    i2 = c2 ? t2 : i2;
    k0 = n0; k1 = n1; k2 = n2;
}

// v_pk_fma_f32 packed distance: lo/hi = two queries; candidate coords
// broadcast via op_sel. IEEE f32 fma per half, z->y->x nesting:
//   e = x*X + (y*Y + (z*Z + w))
#define E2_FROM(p_xy, p_zw, XX, YY, ZZ, e2)                                    \
    do {                                                                       \
        asm("v_pk_fma_f32 %0, %1, %2, %3 op_sel:[0,0,1] op_sel_hi:[0,1,1]"     \
            : "=v"(e2) : "v"(p_zw), "v"(ZZ), "v"(p_zw));                       \
        asm("v_pk_fma_f32 %0, %1, %2, %0 op_sel:[1,0,0] op_sel_hi:[1,1,1]"     \
            : "+v"(e2) : "v"(p_xy), "v"(YY));                                  \
        asm("v_pk_fma_f32 %0, %1, %2, %0 op_sel:[0,0,0] op_sel_hi:[0,1,1]"     \
            : "+v"(e2) : "v"(p_xy), "v"(XX));                                  \
    } while (0)

#define PK_LO(acc, ap, bw)                                                     \
    asm("v_pk_fma_f32 %0, %1, %2, %0 op_sel:[0,0,0] op_sel_hi:[0,1,1]"         \
        : "+v"(acc) : "v"(ap), "v"(bw))
#define PK_HI(acc, ap, bw)                                                     \
    asm("v_pk_fma_f32 %0, %1, %2, %0 op_sel:[1,0,0] op_sel_hi:[1,1,1]"         \
        : "+v"(acc) : "v"(ap), "v"(bw))

// ---------------------------------------------------------------------------
// knn phase (NPT=2): VALUE-ONLY exact top-3 per 256-candidate sub-chunk
// (unchanged from round 5: 85.5us proven). nb==0 blocks additionally dump
// their staged (x,y,z,|p|^2) chunk to the global cand4 array for k_resolve.
// ---------------------------------------------------------------------------
__device__ __forceinline__ void knn_phase(int id, int t, float* smem,
                                          const float* __restrict__ xyz1,
                                          const float* __restrict__ xyz2,
                                          float* __restrict__ pv,
                                          float4* __restrict__ cand4) {
    int nb = id & 31;
    int ch = (id >> 5) & 7;
    int b  = id >> 8;
    int s0 = ch * SCS;

    float4* smv = (float4*)smem;
    const float* x2 = xyz2 + (size_t)b * 3 * SS;
    for (int i = t; i < SCS; i += 256) {
        float px = x2[s0 + i];
        float py = x2[SS + s0 + i];
        float pz = x2[2 * SS + s0 + i];
        float4 p4 = make_float4(px, py, pz, fmaf(px, px, fmaf(py, py, pz * pz)));
        smv[i] = p4;
        if (nb == 0) cand4[(size_t)b * SS + s0 + i] = p4;   // 32 dump blocks
    }
    __syncthreads();

    int n0  = nb * 512 + t;
    int n1q = n0 + 256;
    const float* xb = xyz1 + (size_t)b * 3 * NN;
    float ax = xb[n0],  ay = xb[NN + n0],  az = xb[2 * NN + n0];
    float bx = xb[n1q], by = xb[NN + n1q], bz = xb[2 * NN + n1q];
    v2f XX = {-2.0f * ax, -2.0f * bx};
    v2f YY = {-2.0f * ay, -2.0f * by};
    v2f ZZ = {-2.0f * az, -2.0f * bz};

#pragma unroll
    for (int half = 0; half < 2; ++half) {
        float A0 = 1e30f, A1 = 1e30f, A2 = 1e30f;
        float B0 = 1e30f, B1 = 1e30f, B2 = 1e30f;
        int sb = half * SUBL;
#pragma unroll 8
        for (int s = sb; s < sb + SUBL; ++s) {
            v4f p = *(const v4f*)(smem + 4 * s);
            v2f pxy = __builtin_shufflevector(p, p, 0, 1);
            v2f pzw = __builtin_shufflevector(p, p, 2, 3);
            v2f e2;
            E2_FROM(pxy, pzw, XX, YY, ZZ, e2);
            float nA1 = __builtin_amdgcn_fmed3f(e2.x, A0, A1);
            float nA2 = __builtin_amdgcn_fmed3f(e2.x, A1, A2);
            A0 = fminf(A0, e2.x); A1 = nA1; A2 = nA2;
            float nB1 = __builtin_amdgcn_fmed3f(e2.y, B0, B1);
            float nB2 = __builtin_amdgcn_fmed3f(e2.y, B1, B2);
            B0 = fminf(B0, e2.y); B1 = nB1; B2 = nB2;
        }
        int sub = ch * 2 + half;
        size_t base = (size_t)(sub * BB + b) * 3;
        pv[(base + 0) * NN + n0]  = A0;
        pv[(base + 1) * NN + n0]  = A1;
        pv[(base + 2) * NN + n0]  = A2;
        pv[(base + 0) * NN + n1q] = B0;
        pv[(base + 1) * NN + n1q] = B1;
        pv[(base + 2) * NN + n1q] = B2;
    }
}

// ---------------------------------------------------------------------------
// gemm phase: 64s x 64o tile, 4x4 micro via 8 v_pk_fma_f32 per cc (unchanged).
// ---------------------------------------------------------------------------
__device__ __forceinline__ void gemm_phase(int g, int t, float* smem,
                                           const float* __restrict__ P,
                                           const float* __restrict__ W,
                                           const float* __restrict__ bias,
                                           unsigned short* __restrict__ Gh) {
    int o0 = (g & 3) * 64;
    int s0 = ((g >> 2) & 63) * 64;
    int b  = g >> 8;
    float* sP = smem;              // 16 x 64
    float* sW = smem + 1024;       // 16 x 68 (padded)
    int i = t & 15;
    int j = t >> 4;

    v2f acc2[4][2];
#pragma unroll
    for (int p = 0; p < 4; ++p) {
        acc2[p][0] = (v2f){0.f, 0.f};
        acc2[p][1] = (v2f){0.f, 0.f};
    }

    const float* Pb = P + (size_t)b * CIN * SS;

    for (int c0 = 0; c0 < CIN; c0 += 16) {
        __syncthreads();
        {
            int col = t & 63;
            int r0r = t >> 6;
#pragma unroll
            for (int r = 0; r < 4; ++r) {
                int row = r0r + r * 4;
                sP[row * 64 + col] = Pb[(size_t)(c0 + row) * SS + s0 + col];
            }
        }
        {
            int cc = t & 15;
            int obase = t >> 4;
#pragma unroll
            for (int r = 0; r < 4; ++r) {
                int oo = obase + 16 * r;
                sW[cc * 68 + oo] = W[(size_t)(o0 + oo) * CIN + c0 + cc];
            }
        }
        __syncthreads();

#pragma unroll
        for (int cc = 0; cc < 16; ++cc) {
            v4f a  = *(const v4f*)&sP[cc * 64 + i * 4];
            v4f bv = *(const v4f*)&sW[cc * 68 + j * 4];
            v2f a01 = __builtin_shufflevector(a, a, 0, 1);
            v2f a23 = __builtin_shufflevector(a, a, 2, 3);
            v2f b01 = __builtin_shufflevector(bv, bv, 0, 1);
            v2f b23 = __builtin_shufflevector(bv, bv, 2, 3);
            PK_LO(acc2[0][0], a01, b01); PK_LO(acc2[0][1], a01, b23);  // a.x
            PK_HI(acc2[1][0], a01, b01); PK_HI(acc2[1][1], a01, b23);  // a.y
            PK_LO(acc2[2][0], a23, b01); PK_LO(acc2[2][1], a23, b23);  // a.z
            PK_HI(acc2[3][0], a23, b01); PK_HI(acc2[3][1], a23, b23);  // a.w
        }
    }

    float b0 = bias[o0 + j * 4 + 0];
    float b1 = bias[o0 + j * 4 + 1];
    float b2 = bias[o0 + j * 4 + 2];
    float b3 = bias[o0 + j * 4 + 3];
#pragma unroll
    for (int p = 0; p < 4; ++p) {
        ushort4 v;
        v.x = f2bf(acc2[p][0].x + b0);
        v.y = f2bf(acc2[p][0].y + b1);
        v.z = f2bf(acc2[p][1].x + b2);
        v.w = f2bf(acc2[p][1].y + b3);
        size_t off = ((size_t)b * SS + s0 + i * 4 + p) * COUT + o0 + j * 4;
        *(ushort4*)&Gh[off] = v;
    }
}

// ---------------------------------------------------------------------------
__global__ __launch_bounds__(256) void k_fused(const float* __restrict__ xyz1,
                                               const float* __restrict__ xyz2,
                                               const float* __restrict__ P,
                                               const float* __restrict__ W,
                                               const float* __restrict__ bias,
                                               unsigned short* __restrict__ Gh,
                                               float* __restrict__ pv,
                                               float4* __restrict__ cand4) {
    __shared__ float smem[2112];   // 8.25 KB: knn 512 float4 / gemm sP+sW
    int bid = blockIdx.x;
    int t   = threadIdx.x;

    if (bid < KNNB) {
        knn_phase(bid, t, smem, xyz1, xyz2, pv, cand4);
    } else {
        gemm_phase(bid - KNNB, t, smem, P, W, bias, Gh);
    }
}

// ---------------------------------------------------------------------------
// Resolve v2: one thread per (query, slot). Block = 64 queries x 4 slots;
// wave k handles slot k for 64 consecutive queries (coalesced pv loads).
// Each slot thread: fold 48 values -> global v0<=v1<=v2; screen sub-mins
// (cached in regs) -> l_k = k-th winning sub, cnt; scan 256 candidates of
// l_k from global cand4 (lanes walk consecutive 16B -> 4x L1-line reuse),
// exact stable insert_vi. Slot triples merged in-block via LDS in ascending
// sub order (== proven k_merge fold semantics). cnt>4 tie pathology: slot 0
// scans all subs, slots 1-3 emit identity. 16 waves/CU (was 1 wave/SIMD).
// ---------------------------------------------------------------------------
__global__ __launch_bounds__(256) void k_resolve(const float* __restrict__ pv,
                                                 const float* __restrict__ xyz1,
                                                 const float4* __restrict__ cand4,
                                                 float4* __restrict__ wi4,
                                                 int4* __restrict__ gi4) {
    __shared__ float sv[4][64][3];
    __shared__ int   si[4][64][3];
    int bid  = blockIdx.x;
    int b    = bid >> 8;          // 256 blocks per batch
    int nblk = bid & 255;
    int t    = threadIdx.x;
    int k    = t >> 6;            // slot 0..3 (one wave per slot)
    int q    = t & 63;
    int n    = nblk * 64 + q;

    // fold 48 per-sub values -> global top-3 values; cache sub-mins in regs
    float a0s[SUBS];
    float v0 = 1e30f, v1 = 1e30f, v2v = 1e30f;
#pragma unroll
    for (int sub = 0; sub < SUBS; ++sub) {
        size_t base = (size_t)(sub * BB + b) * 3;
#pragma unroll
        for (int j = 0; j < 3; ++j) {
            float a = pv[(base + j) * NN + n];
            if (j == 0) a0s[sub] = a;
            float t1 = __builtin_amdgcn_fmed3f(a, v0, v1);
            float t2 = __builtin_amdgcn_fmed3f(a, v1, v2v);
            v0 = fminf(v0, a); v1 = t1; v2v = t2;
        }
    }

    // screen: l_k = k-th winning sub (ascending), cnt = winning-sub count
    int lk = 0, cnt = 0;
#pragma unroll
    for (int sub = 0; sub < SUBS; ++sub) {
        bool w = (a0s[sub] <= v2v);
        if (w && cnt == k) lk = sub;
        cnt += w ? 1 : 0;
    }

    float k0 = 1e30f, k1 = 1e30f, k2 = 1e30f;
    int   i0 = 0,     i1 = 0,     i2 = 0;
    bool ovf = (cnt > 4);                       // exact-tie pathology
    bool act = !ovf && (k < cnt);
    const float* xb = xyz1 + (size_t)b * 3 * NN;
    float qx = xb[n], qy = xb[NN + n], qz = xb[2 * NN + n];
    float xm2 = -2.0f * qx, ym2 = -2.0f * qy, zm2 = -2.0f * qz;
    const float4* cb = cand4 + (size_t)b * SS;

    if (act) {                                  // normal path: scan one sub
        int sb = lk * SUBL;
#pragma unroll 4
        for (int s = 0; s < SUBL; ++s) {
            float4 p = cb[sb + s];
            float e = fmaf(p.x, xm2, fmaf(p.y, ym2, fmaf(p.z, zm2, p.w)));
            insert_vi(e, sb + s, k0, k1, k2, i0, i1, i2);
        }
    }
    if (__any(ovf && k == 0)) {                 // rare: full exact fallback
        if (ovf && k == 0) {
            for (int s = 0; s < SS; ++s) {
                float4 p = cb[s];
                float e = fmaf(p.x, xm2, fmaf(p.y, ym2, fmaf(p.z, zm2, p.w)));
                insert_vi(e, s, k0, k1, k2, i0, i1, i2);
            }
        }
    }

    sv[k][q][0] = k0; sv[k][q][1] = k1; sv[k][q][2] = k2;
    si[k][q][0] = i0; si[k][q][1] = i1; si[k][q][2] = i2;
    __syncthreads();

    if (t < 64) {                               // wave 0 merges + weights
        float K0 = 1e30f, K1 = 1e30f, K2 = 1e30f;
        int   I0 = 0,     I1 = 0,     I2 = 0;
#pragma unroll
        for (int kk = 0; kk < 4; ++kk)
#pragma unroll
            for (int j = 0; j < 3; ++j)
                insert_vi(sv[kk][t][j], si[kk][t][j], K0, K1, K2, I0, I1, I2);

        int nn = nblk * 64 + t;
        float ax = xb[nn], ay = xb[NN + nn], az = xb[2 * NN + nn];
        float nrm = fmaf(ax, ax, fmaf(ay, ay, az * az));
        float d0 = K0 + nrm, d1 = K1 + nrm, d2 = K2 + nrm;
        float r0 = 1.0f / (d0 + 1e-8f);
        float r1 = 1.0f / (d1 + 1e-8f);
        float r2 = 1.0f / (d2 + 1e-8f);
        float inv = 1.0f / (r0 + r1 + r2);
        size_t oq = (size_t)b * NN + nn;
        wi4[oq] = make_float4(r0 * inv, r1 * inv, r2 * inv, 0.f);
        gi4[oq] = make_int4(I0, I1, I2, 0);
    }
}

// ---------------------------------------------------------------------------
// Output: unchanged (XCD-swizzled flat grid, 64q x 64ch blocks,
// 4-query/wave MLP gather, stride-68 tile, coalesced stores).
// ---------------------------------------------------------------------------
__global__ __launch_bounds__(256) void k_out(const unsigned short* __restrict__ Gh,
                                             const float4* __restrict__ wi4,
                                             const int4* __restrict__ gi4,
                                             float* __restrict__ out) {
    __shared__ float  tile[64 * 68];   // 17.4 KB
    __shared__ float4 swv[64];
    __shared__ int4   siv[64];
    int bid  = blockIdx.x;
    int x    = bid & 7;                // XCD slot (blockIdx % 8 round-robin)
    int b    = x >> 1;                 // 2 XCDs per batch
    int local = (bid >> 3) + (x & 1) * 512;   // 0..1023 per batch
    int nb   = local & 255;            // 256 n-blocks
    int oc   = local >> 8;             // 4 o-chunks
    int n0   = nb * 64;
    int o0   = oc * 64;
    int t    = threadIdx.x;
    int wave = t >> 6;
    int lane = t & 63;
    int qg   = lane >> 4;     // query-in-group 0..3
    int c16  = lane & 15;     // channel quad 0..15

    if (t < 64) {
        size_t q = (size_t)b * NN + n0 + t;
        swv[t] = wi4[q];
        siv[t] = gi4[q];
    }
    __syncthreads();

    const unsigned short* Gb = Gh + (size_t)b * SS * COUT;

#pragma unroll
    for (int pass = 0; pass < 4; ++pass) {
        int q = pass * 16 + wave * 4 + qg;
        float4 wv = swv[q];
        int4   iv = siv[q];
        int co = o0 + c16 * 4;
        ushort4 a0 = *(const ushort4*)(Gb + (size_t)iv.x * COUT + co);
        ushort4 a1 = *(const ushort4*)(Gb + (size_t)iv.y * COUT + co);
        ushort4 a2 = *(const ushort4*)(Gb + (size_t)iv.z * COUT + co);
        float4 v;
        v.x = fmaf(wv.x, bf2f(a0.x), fmaf(wv.y, bf2f(a1.x), wv.z * bf2f(a2.x)));
        v.y = fmaf(wv.x, bf2f(a0.y), fmaf(wv.y, bf2f(a1.y), wv.z * bf2f(a2.y)));
        v.z = fmaf(wv.x, bf2f(a0.z), fmaf(wv.y, bf2f(a1.z), wv.z * bf2f(a2.z)));
        v.w = fmaf(wv.x, bf2f(a0.w), fmaf(wv.y, bf2f(a1.w), wv.z * bf2f(a2.w)));
        *(float4*)&tile[q * 68 + c16 * 4] = v;
    }
    __syncthreads();

    float* obase = out + ((size_t)b * COUT + o0) * NN + n0 + lane;
#pragma unroll
    for (int g = 0; g < 4; ++g) {
        int c = wave * 16 + g * 4;
        float4 v = *(const float4*)&tile[lane * 68 + c];
        obase[(size_t)(c + 0) * NN] = v.x;
        obase[(size_t)(c + 1) * NN] = v.y;
        obase[(size_t)(c + 2) * NN] = v.z;
        obase[(size_t)(c + 3) * NN] = v.w;
    }
}

// ---------------------------------------------------------------------------
extern "C" void kernel_launch(void* const* d_in, const int* in_sizes, int n_in,
                              void* d_out, int out_size, void* d_ws, size_t ws_size,
                              hipStream_t stream) {
    const float* xyz1    = (const float*)d_in[0];   // [B,3,N]
    const float* xyz2    = (const float*)d_in[1];   // [B,3,S]
    const float* points2 = (const float*)d_in[2];   // [B,CIN,S]
    const float* W       = (const float*)d_in[3];   // [COUT,CIN]
    const float* bias    = (const float*)d_in[4];   // [COUT]
    float* out = (float*)d_out;                     // [B,COUT,N]

    char* ws = (char*)d_ws;
    // workspace layout (bytes), total 23,068,672 (proven size, unchanged):
    //   pv  : 0        .. 12,582,912  ([SUBS=16][B][3][N] f32 sub top-3 values)
    //   Gh  : 12582912 .. 20,971,520  ([B][S][COUT] bf16)
    //   wi4 : 20971520 .. 22,020,096  ([B][N] float4)
    //   gi4 : 22020096 .. 23,068,672  ([B][N] int4)
    float*          pv  = (float*)(ws);
    unsigned short* Gh  = (unsigned short*)(ws + 12582912);
    float4*         wi4 = (float4*)(ws + 20971520);
    int4*           gi4 = (int4*)(ws + 22020096);
    // cand4 ([B][S] float4 = 256 KB) lives in the TAIL of `out`:
    // written by k_fused, read by k_resolve, overwritten by k_out (stream-
    // ordered). out = 67,108,864 B; tail offset = 67,108,864 - 262,144.
    float4* cand4 = (float4*)((char*)d_out + 66846720);

    k_fused<<<dim3(KNNB + GEMMB), 256, 0, stream>>>(xyz1, xyz2, points2, W, bias,
                                                    Gh, pv, cand4);
    k_resolve<<<dim3(RSLVB), 256, 0, stream>>>(pv, xyz1, cand4, wi4, gi4);
    k_out<<<dim3(4096), 256, 0, stream>>>(Gh, wi4, gi4, out);
}

// Round 7
// 208.776 us; speedup vs baseline: 1.1588x; 1.1588x over previous
//
#include <hip/hip_runtime.h>

#define BB 4
#define NN 16384
#define SS 4096
#define CIN 256
#define COUT 256

#define SC 8                  // s-chunks per knn block pass
#define SCS (SS / SC)         // 512 candidates staged per knn block
#define SUBS 16               // value-dump granularity: 16 subs of 256
#define SUBL 256
#define KNNB ((NN / 512) * SC * BB)           // 32*8*4 = 1024 knn blocks (NPT=2)
#define GEMMB ((COUT / 64) * (SS / 64) * BB)  // 4*64*4 = 1024 gemm blocks
#define RSLVB (BB * NN / 4)                   // 16384 blocks, 1 wave = 1 query

typedef float v2f __attribute__((ext_vector_type(2)));
typedef float v4f __attribute__((ext_vector_type(4)));

__device__ __forceinline__ unsigned short f2bf(float f) {   // RNE float->bf16
    unsigned u = __float_as_uint(f);
    u += 0x7FFF + ((u >> 16) & 1);
    return (unsigned short)(u >> 16);
}
__device__ __forceinline__ float bf2f(unsigned short h) {
    return __uint_as_float((unsigned)h << 16);
}

// Value-only exact top-3 insert (sorted invariant a<=b<=c): 3 full-rate ops.
__device__ __forceinline__ void ins_v(float e, float& a, float& b, float& c) {
    float n1 = __builtin_amdgcn_fmed3f(e, a, b);
    float n2 = __builtin_amdgcn_fmed3f(e, b, c);
    a = fminf(a, e); b = n1; c = n2;
}

// Exact stable top-3 insert, value + index, strict '<' (requires ascending-
// index processing order). Proven passing rounds 3/5/6.
__device__ __forceinline__ void insert_vi(float e, int gi,
                                          float& k0, float& k1, float& k2,
                                          int& i0, int& i1, int& i2) {
    bool c0 = e < k0, c1 = e < k1, c2 = e < k2;
    float n0 = fminf(e, k0);
    float n1 = __builtin_amdgcn_fmed3f(e, k0, k1);
    float n2 = __builtin_amdgcn_fmed3f(e, k1, k2);
    int t1 = c0 ? i0 : gi;
    int t2 = c1 ? i1 : gi;
    i0 = c0 ? gi : i0;
    i1 = c1 ? t1 : i1;
    i2 = c2 ? t2 : i2;
    k0 = n0; k1 = n1; k2 = n2;
}

// Lexicographic (value, index) insert: order-independent exact stable top-3.
// Used only on the <=16 gathered finalists per query.
__device__ __forceinline__ void ins_lex(float e, int gi,
                                        float& k0, float& k1, float& k2,
                                        int& i0, int& i1, int& i2) {
    bool c0 = (e < k0) || (e == k0 && gi < i0);
    bool c1 = (e < k1) || (e == k1 && gi < i1);
    bool c2 = (e < k2) || (e == k2 && gi < i2);
    float n0 = fminf(e, k0);
    float n1 = __builtin_amdgcn_fmed3f(e, k0, k1);
    float n2 = __builtin_amdgcn_fmed3f(e, k1, k2);
    int t1 = c0 ? i0 : gi;
    int t2 = c1 ? i1 : gi;
    i0 = c0 ? gi : i0;
    i1 = c1 ? t1 : i1;
    i2 = c2 ? t2 : i2;
    k0 = n0; k1 = n1; k2 = n2;
}

// popcount of mask bits strictly below this lane
__device__ __forceinline__ int ltc(unsigned long long m) {
    return __builtin_amdgcn_mbcnt_hi(
        (unsigned)(m >> 32), __builtin_amdgcn_mbcnt_lo((unsigned)m, 0));
}

// v_pk_fma_f32 packed distance: lo/hi = two queries; candidate coords
// broadcast via op_sel. IEEE f32 fma per half, z->y->x nesting:
//   e = x*X + (y*Y + (z*Z + w))
#define E2_FROM(p_xy, p_zw, XX, YY, ZZ, e2)                                    \
    do {                                                                       \
        asm("v_pk_fma_f32 %0, %1, %2, %3 op_sel:[0,0,1] op_sel_hi:[0,1,1]"     \
            : "=v"(e2) : "v"(p_zw), "v"(ZZ), "v"(p_zw));                       \
        asm("v_pk_fma_f32 %0, %1, %2, %0 op_sel:[1,0,0] op_sel_hi:[1,1,1]"     \
            : "+v"(e2) : "v"(p_xy), "v"(YY));                                  \
        asm("v_pk_fma_f32 %0, %1, %2, %0 op_sel:[0,0,0] op_sel_hi:[0,1,1]"     \
            : "+v"(e2) : "v"(p_xy), "v"(XX));                                  \
    } while (0)

#define PK_LO(acc, ap, bw)                                                     \
    asm("v_pk_fma_f32 %0, %1, %2, %0 op_sel:[0,0,0] op_sel_hi:[0,1,1]"         \
        : "+v"(acc) : "v"(ap), "v"(bw))
#define PK_HI(acc, ap, bw)                                                     \
    asm("v_pk_fma_f32 %0, %1, %2, %0 op_sel:[1,0,0] op_sel_hi:[1,1,1]"         \
        : "+v"(acc) : "v"(ap), "v"(bw))

// ---------------------------------------------------------------------------
// knn phase (NPT=2): VALUE-ONLY exact top-3 per 256-candidate sub-chunk
// (unchanged, 84.4us proven). nb==0 blocks dump the staged (x,y,z,|p|^2)
// chunk to global cand4 for k_resolve.
// ---------------------------------------------------------------------------
__device__ __forceinline__ void knn_phase(int id, int t, float* smem,
                                          const float* __restrict__ xyz1,
                                          const float* __restrict__ xyz2,
                                          float* __restrict__ pv,
                                          float4* __restrict__ cand4) {
    int nb = id & 31;
    int ch = (id >> 5) & 7;
    int b  = id >> 8;
    int s0 = ch * SCS;

    float4* smv = (float4*)smem;
    const float* x2 = xyz2 + (size_t)b * 3 * SS;
    for (int i = t; i < SCS; i += 256) {
        float px = x2[s0 + i];
        float py = x2[SS + s0 + i];
        float pz = x2[2 * SS + s0 + i];
        float4 p4 = make_float4(px, py, pz, fmaf(px, px, fmaf(py, py, pz * pz)));
        smv[i] = p4;
        if (nb == 0) cand4[(size_t)b * SS + s0 + i] = p4;   // 32 dump blocks
    }
    __syncthreads();

    int n0  = nb * 512 + t;
    int n1q = n0 + 256;
    const float* xb = xyz1 + (size_t)b * 3 * NN;
    float ax = xb[n0],  ay = xb[NN + n0],  az = xb[2 * NN + n0];
    float bx = xb[n1q], by = xb[NN + n1q], bz = xb[2 * NN + n1q];
    v2f XX = {-2.0f * ax, -2.0f * bx};
    v2f YY = {-2.0f * ay, -2.0f * by};
    v2f ZZ = {-2.0f * az, -2.0f * bz};

#pragma unroll
    for (int half = 0; half < 2; ++half) {
        float A0 = 1e30f, A1 = 1e30f, A2 = 1e30f;
        float B0 = 1e30f, B1 = 1e30f, B2 = 1e30f;
        int sb = half * SUBL;
#pragma unroll 8
        for (int s = sb; s < sb + SUBL; ++s) {
            v4f p = *(const v4f*)(smem + 4 * s);
            v2f pxy = __builtin_shufflevector(p, p, 0, 1);
            v2f pzw = __builtin_shufflevector(p, p, 2, 3);
            v2f e2;
            E2_FROM(pxy, pzw, XX, YY, ZZ, e2);
            float nA1 = __builtin_amdgcn_fmed3f(e2.x, A0, A1);
            float nA2 = __builtin_amdgcn_fmed3f(e2.x, A1, A2);
            A0 = fminf(A0, e2.x); A1 = nA1; A2 = nA2;
            float nB1 = __builtin_amdgcn_fmed3f(e2.y, B0, B1);
            float nB2 = __builtin_amdgcn_fmed3f(e2.y, B1, B2);
            B0 = fminf(B0, e2.y); B1 = nB1; B2 = nB2;
        }
        int sub = ch * 2 + half;
        size_t base = (size_t)(sub * BB + b) * 3;
        pv[(base + 0) * NN + n0]  = A0;
        pv[(base + 1) * NN + n0]  = A1;
        pv[(base + 2) * NN + n0]  = A2;
        pv[(base + 0) * NN + n1q] = B0;
        pv[(base + 1) * NN + n1q] = B1;
        pv[(base + 2) * NN + n1q] = B2;
    }
}

// ---------------------------------------------------------------------------
// gemm phase: 64s x 64o tile, 4x4 micro via 8 v_pk_fma_f32 per cc (unchanged).
// ---------------------------------------------------------------------------
__device__ __forceinline__ void gemm_phase(int g, int t, float* smem,
                                           const float* __restrict__ P,
                                           const float* __restrict__ W,
                                           const float* __restrict__ bias,
                                           unsigned short* __restrict__ Gh) {
    int o0 = (g & 3) * 64;
    int s0 = ((g >> 2) & 63) * 64;
    int b  = g >> 8;
    float* sP = smem;              // 16 x 64
    float* sW = smem + 1024;       // 16 x 68 (padded)
    int i = t & 15;
    int j = t >> 4;

    v2f acc2[4][2];
#pragma unroll
    for (int p = 0; p < 4; ++p) {
        acc2[p][0] = (v2f){0.f, 0.f};
        acc2[p][1] = (v2f){0.f, 0.f};
    }

    const float* Pb = P + (size_t)b * CIN * SS;

    for (int c0 = 0; c0 < CIN; c0 += 16) {
        __syncthreads();
        {
            int col = t & 63;
            int r0r = t >> 6;
#pragma unroll
            for (int r = 0; r < 4; ++r) {
                int row = r0r + r * 4;
                sP[row * 64 + col] = Pb[(size_t)(c0 + row) * SS + s0 + col];
            }
        }
        {
            int cc = t & 15;
            int obase = t >> 4;
#pragma unroll
            for (int r = 0; r < 4; ++r) {
                int oo = obase + 16 * r;
                sW[cc * 68 + oo] = W[(size_t)(o0 + oo) * CIN + c0 + cc];
            }
        }
        __syncthreads();

#pragma unroll
        for (int cc = 0; cc < 16; ++cc) {
            v4f a  = *(const v4f*)&sP[cc * 64 + i * 4];
            v4f bv = *(const v4f*)&sW[cc * 68 + j * 4];
            v2f a01 = __builtin_shufflevector(a, a, 0, 1);
            v2f a23 = __builtin_shufflevector(a, a, 2, 3);
            v2f b01 = __builtin_shufflevector(bv, bv, 0, 1);
            v2f b23 = __builtin_shufflevector(bv, bv, 2, 3);
            PK_LO(acc2[0][0], a01, b01); PK_LO(acc2[0][1], a01, b23);  // a.x
            PK_HI(acc2[1][0], a01, b01); PK_HI(acc2[1][1], a01, b23);  // a.y
            PK_LO(acc2[2][0], a23, b01); PK_LO(acc2[2][1], a23, b23);  // a.z
            PK_HI(acc2[3][0], a23, b01); PK_HI(acc2[3][1], a23, b23);  // a.w
        }
    }

    float b0 = bias[o0 + j * 4 + 0];
    float b1 = bias[o0 + j * 4 + 1];
    float b2 = bias[o0 + j * 4 + 2];
    float b3 = bias[o0 + j * 4 + 3];
#pragma unroll
    for (int p = 0; p < 4; ++p) {
        ushort4 v;
        v.x = f2bf(acc2[p][0].x + b0);
        v.y = f2bf(acc2[p][0].y + b1);
        v.z = f2bf(acc2[p][1].x + b2);
        v.w = f2bf(acc2[p][1].y + b3);
        size_t off = ((size_t)b * SS + s0 + i * 4 + p) * COUT + o0 + j * 4;
        *(ushort4*)&Gh[off] = v;
    }
}

// ---------------------------------------------------------------------------
__global__ __launch_bounds__(256) void k_fused(const float* __restrict__ xyz1,
                                               const float* __restrict__ xyz2,
                                               const float* __restrict__ P,
                                               const float* __restrict__ W,
                                               const float* __restrict__ bias,
                                               unsigned short* __restrict__ Gh,
                                               float* __restrict__ pv,
                                               float4* __restrict__ cand4) {
    __shared__ float smem[2112];   // 8.25 KB: knn 512 float4 / gemm sP+sW
    int bid = blockIdx.x;
    int t   = threadIdx.x;

    if (bid < KNNB) {
        knn_phase(bid, t, smem, xyz1, xyz2, pv, cand4);
    } else {
        gemm_phase(bid - KNNB, t, smem, P, W, bias, Gh);
    }
}

// ---------------------------------------------------------------------------
// Resolve v3: ONE WAVE PER QUERY (divergence-free, coalesced):
//   fold:   lane l<48 loads pv (sub=l&15, j=l>>4); 6-step shfl_xor butterfly
//           of value-only triples -> every lane holds exact global v0<=v1<=m2.
//   screen: lane l<16 holds sub-l's min (j=0) -> ballot gives wave-uniform
//           winning-sub mask {sub: min_sub <= m2} (superset of top-3 subs,
//           any count handled -> scan is always exact, no fallback needed).
//   scan:   per winning sub (uniform ctz loop), 4 COALESCED 64-lane float4
//           loads (lane l -> candidate sub*256+r*64+l); exact strict-'<'
//           insert_vi per lane (ascending gi => stable).
//   merge:  entries with value <= m2 (generically exactly 3 wave-wide) are
//           rank-compacted via ballot+mbcnt into <=16 LDS slots; lex-insert
//           of those slots = exact stable top-3. cnt3>16 (mass ties) ->
//           broadcast-read serial rescan (correctness-only path).
// ---------------------------------------------------------------------------
__global__ __launch_bounds__(256) void k_resolve(const float* __restrict__ pv,
                                                 const float* __restrict__ xyz1,
                                                 const float4* __restrict__ cand4,
                                                 float4* __restrict__ wi4,
                                                 int4* __restrict__ gi4) {
    __shared__ uint2 sl[4][16];    // 512 B: per-wave finalist slots
    int t   = threadIdx.x;
    int wid = t >> 6;
    int l   = t & 63;
    int g   = blockIdx.x * 4 + wid;
    int b   = g >> 14;             // g / NN
    int n   = g & (NN - 1);

    // ---- fold ----
    float ov = 1e30f;
    if (l < 48)
        ov = pv[(size_t)(((l & 15) * BB + b) * 3 + (l >> 4)) * NN + n];
    float m0 = ov, m1 = 1e30f, m2 = 1e30f;
#pragma unroll
    for (int xm = 1; xm < 64; xm <<= 1) {
        float s0 = __shfl_xor(m0, xm);
        float s1 = __shfl_xor(m1, xm);
        float s2 = __shfl_xor(m2, xm);
        ins_v(s0, m0, m1, m2);
        ins_v(s1, m0, m1, m2);
        ins_v(s2, m0, m1, m2);
    }
    // m2 == exact global 3rd-smallest shifted distance

    // ---- screen ----
    unsigned mm = (unsigned)__ballot((l < 16) && (ov <= m2)) & 0xFFFFu;

    const float* xb = xyz1 + (size_t)b * 3 * NN;   // b,n wave-uniform
    float qx = xb[n], qy = xb[NN + n], qz = xb[2 * NN + n];
    float xm2c = -2.0f * qx, ym2c = -2.0f * qy, zm2c = -2.0f * qz;
    const float4* cb = cand4 + (size_t)b * SS;

    // ---- scan (coalesced) ----
    float k0 = 1e30f, k1 = 1e30f, k2 = 1e30f;
    int   i0 = 0,     i1 = 0,     i2 = 0;
    unsigned msc = mm;
    while (msc) {
        int sub = __builtin_ctz(msc); msc &= msc - 1;
        int sb = sub * SUBL;
#pragma unroll
        for (int r = 0; r < 4; ++r) {
            int gi = sb + r * 64 + l;
            float4 p = cb[gi];
            float e = fmaf(p.x, xm2c, fmaf(p.y, ym2c, fmaf(p.z, zm2c, p.w)));
            insert_vi(e, gi, k0, k1, k2, i0, i1, i2);
        }
    }

    // ---- merge ----
    unsigned long long b0 = __ballot(k0 <= m2);
    unsigned long long b1 = __ballot(k1 <= m2);
    unsigned long long b2 = __ballot(k2 <= m2);
    int p0 = __popcll(b0), p1 = __popcll(b1);
    int cnt3 = p0 + p1 + __popcll(b2);
    if (cnt3 <= 16) {
        if (k0 <= m2) sl[wid][ltc(b0)]           = make_uint2(__float_as_uint(k0), (unsigned)i0);
        if (k1 <= m2) sl[wid][p0 + ltc(b1)]      = make_uint2(__float_as_uint(k1), (unsigned)i1);
        if (k2 <= m2) sl[wid][p0 + p1 + ltc(b2)] = make_uint2(__float_as_uint(k2), (unsigned)i2);
    }
    __syncthreads();   // uniform: every wave reaches it regardless of cnt3

    float K0 = 1e30f, K1 = 1e30f, K2 = 1e30f;
    int   I0 = 0,     I1 = 0,     I2 = 0;
    if (cnt3 <= 16) {
        for (int j = 0; j < cnt3; ++j) {
            uint2 u = sl[wid][j];
            ins_lex(__uint_as_float(u.x), (int)u.y, K0, K1, K2, I0, I1, I2);
        }
    } else {           // mass-tie pathology: exact serial rescan (broadcast)
        unsigned mf = mm;
        while (mf) {
            int sub = __builtin_ctz(mf); mf &= mf - 1;
            int sb = sub * SUBL;
            for (int s = 0; s < SUBL; ++s) {
                float4 p = cb[sb + s];
                float e = fmaf(p.x, xm2c, fmaf(p.y, ym2c, fmaf(p.z, zm2c, p.w)));
                ins_lex(e, sb + s, K0, K1, K2, I0, I1, I2);
            }
        }
    }

    if (l == 0) {
        float nrm = fmaf(qx, qx, fmaf(qy, qy, qz * qz));
        float d0 = K0 + nrm, d1 = K1 + nrm, d2 = K2 + nrm;
        float r0 = 1.0f / (d0 + 1e-8f);
        float r1 = 1.0f / (d1 + 1e-8f);
        float r2 = 1.0f / (d2 + 1e-8f);
        float inv = 1.0f / (r0 + r1 + r2);
        size_t oq = (size_t)b * NN + n;
        wi4[oq] = make_float4(r0 * inv, r1 * inv, r2 * inv, 0.f);
        gi4[oq] = make_int4(I0, I1, I2, 0);
    }
}

// ---------------------------------------------------------------------------
// Output: unchanged (XCD-swizzled flat grid, 64q x 64ch blocks,
// 4-query/wave MLP gather, stride-68 tile, coalesced stores).
// ---------------------------------------------------------------------------
__global__ __launch_bounds__(256) void k_out(const unsigned short* __restrict__ Gh,
                                             const float4* __restrict__ wi4,
                                             const int4* __restrict__ gi4,
                                             float* __restrict__ out) {
    __shared__ float  tile[64 * 68];   // 17.4 KB
    __shared__ float4 swv[64];
    __shared__ int4   siv[64];
    int bid  = blockIdx.x;
    int x    = bid & 7;                // XCD slot (blockIdx % 8 round-robin)
    int b    = x >> 1;                 // 2 XCDs per batch
    int local = (bid >> 3) + (x & 1) * 512;   // 0..1023 per batch
    int nb   = local & 255;            // 256 n-blocks
    int oc   = local >> 8;             // 4 o-chunks
    int n0   = nb * 64;
    int o0   = oc * 64;
    int t    = threadIdx.x;
    int wave = t >> 6;
    int lane = t & 63;
    int qg   = lane >> 4;     // query-in-group 0..3
    int c16  = lane & 15;     // channel quad 0..15

    if (t < 64) {
        size_t q = (size_t)b * NN + n0 + t;
        swv[t] = wi4[q];
        siv[t] = gi4[q];
    }
    __syncthreads();

    const unsigned short* Gb = Gh + (size_t)b * SS * COUT;

#pragma unroll
    for (int pass = 0; pass < 4; ++pass) {
        int q = pass * 16 + wave * 4 + qg;
        float4 wv = swv[q];
        int4   iv = siv[q];
        int co = o0 + c16 * 4;
        ushort4 a0 = *(const ushort4*)(Gb + (size_t)iv.x * COUT + co);
        ushort4 a1 = *(const ushort4*)(Gb + (size_t)iv.y * COUT + co);
        ushort4 a2 = *(const ushort4*)(Gb + (size_t)iv.z * COUT + co);
        float4 v;
        v.x = fmaf(wv.x, bf2f(a0.x), fmaf(wv.y, bf2f(a1.x), wv.z * bf2f(a2.x)));
        v.y = fmaf(wv.x, bf2f(a0.y), fmaf(wv.y, bf2f(a1.y), wv.z * bf2f(a2.y)));
        v.z = fmaf(wv.x, bf2f(a0.z), fmaf(wv.y, bf2f(a1.z), wv.z * bf2f(a2.z)));
        v.w = fmaf(wv.x, bf2f(a0.w), fmaf(wv.y, bf2f(a1.w), wv.z * bf2f(a2.w)));
        *(float4*)&tile[q * 68 + c16 * 4] = v;
    }
    __syncthreads();

    float* obase = out + ((size_t)b * COUT + o0) * NN + n0 + lane;
#pragma unroll
    for (int g = 0; g < 4; ++g) {
        int c = wave * 16 + g * 4;
        float4 v = *(const float4*)&tile[lane * 68 + c];
        obase[(size_t)(c + 0) * NN] = v.x;
        obase[(size_t)(c + 1) * NN] = v.y;
        obase[(size_t)(c + 2) * NN] = v.z;
        obase[(size_t)(c + 3) * NN] = v.w;
    }
}

// ---------------------------------------------------------------------------
extern "C" void kernel_launch(void* const* d_in, const int* in_sizes, int n_in,
                              void* d_out, int out_size, void* d_ws, size_t ws_size,
                              hipStream_t stream) {
    const float* xyz1    = (const float*)d_in[0];   // [B,3,N]
    const float* xyz2    = (const float*)d_in[1];   // [B,3,S]
    const float* points2 = (const float*)d_in[2];   // [B,CIN,S]
    const float* W       = (const float*)d_in[3];   // [COUT,CIN]
    const float* bias    = (const float*)d_in[4];   // [COUT]
    float* out = (float*)d_out;                     // [B,COUT,N]

    char* ws = (char*)d_ws;
    // workspace layout (bytes), total 23,068,672 (proven size, unchanged):
    //   pv  : 0        .. 12,582,912  ([SUBS=16][B][3][N] f32 sub top-3 values)
    //   Gh  : 12582912 .. 20,971,520  ([B][S][COUT] bf16)
    //   wi4 : 20971520 .. 22,020,096  ([B][N] float4)
    //   gi4 : 22020096 .. 23,068,672  ([B][N] int4)
    float*          pv  = (float*)(ws);
    unsigned short* Gh  = (unsigned short*)(ws + 12582912);
    float4*         wi4 = (float4*)(ws + 20971520);
    int4*           gi4 = (int4*)(ws + 22020096);
    // cand4 ([B][S] float4 = 256 KB) lives in the TAIL of `out`:
    // written by k_fused, read by k_resolve, overwritten by k_out (stream-
    // ordered). out = 67,108,864 B; tail offset = 67,108,864 - 262,144.
    float4* cand4 = (float4*)((char*)d_out + 66846720);

    k_fused<<<dim3(KNNB + GEMMB), 256, 0, stream>>>(xyz1, xyz2, points2, W, bias,
                                                    Gh, pv, cand4);
    k_resolve<<<dim3(RSLVB), 256, 0, stream>>>(pv, xyz1, cand4, wi4, gi4);
    k_out<<<dim3(4096), 256, 0, stream>>>(Gh, wi4, gi4, out);
}